// Round 7
// baseline (3622.422 us; speedup 1.0000x reference)
//
#include <hip/hip_runtime.h>
#include <hip/hip_bf16.h>
#include <cstdint>
#include <cstddef>

// Problem constants
#define TT 1024
#define BB 32
#define DD 1024
#define HH 512
#define GG 2048  // 4H

// f16 -inf bit pattern replicated; |h|<1 so a valid packed h can never be it
#define POISON_U64 0xFC00FC00FC00FC00ull

typedef _Float16 f16x8 __attribute__((ext_vector_type(8)));
typedef _Float16 f16x4 __attribute__((ext_vector_type(4)));
typedef float    f32x4 __attribute__((ext_vector_type(4)));

__device__ __forceinline__ float sigm(float x) { return 1.0f / (1.0f + __expf(-x)); }
__device__ __forceinline__ float tanh_fast(float x) { return 2.0f / (1.0f + __expf(-2.0f * x)) - 1.0f; }

// ---------------------------------------------------------------------------
// init: hring = [chain8][slot4][1024] u64 (chain = dir*4+grp), u64 = 4xf16 h.
// Slot for step s is s&3. Slot 0 = h(0) = all-zero (valid: low f16 = 0 !=
// poison). Slots 1..3 = poison. 8*4*1024 = 32768 u64 -> 128 x 256.
// ---------------------------------------------------------------------------
__global__ __launch_bounds__(256) void init_kernel(unsigned long long* __restrict__ hr) {
    const int i = blockIdx.x * 256 + threadIdx.x;
    const int slot = (i >> 10) & 3;
    hr[i] = (slot == 0) ? 0ull : POISON_U64;
}

// ---------------------------------------------------------------------------
// transpose_f16: in fp32 [K][N] row-major -> out f16 [N][K].
// ---------------------------------------------------------------------------
__global__ __launch_bounds__(256) void transpose_f16(const float* __restrict__ in,
                                                     _Float16* __restrict__ out,
                                                     int K, int N) {
    __shared__ float tile[32][33];
    const int tx = threadIdx.x & 31, ty = threadIdx.x >> 5;
    const int n0 = blockIdx.x * 32, k0 = blockIdx.y * 32;
#pragma unroll
    for (int j = 0; j < 4; j++)
        tile[ty + 8 * j][tx] = in[(size_t)(k0 + ty + 8 * j) * N + n0 + tx];
    __syncthreads();
#pragma unroll
    for (int j = 0; j < 4; j++)
        out[(size_t)(n0 + ty + 8 * j) * K + k0 + tx] = (_Float16)tile[tx][ty + 8 * j];
}

// ---------------------------------------------------------------------------
// Phase 1: xg = x@Wx + b via MFMA f16 (fp32 accumulate), stored f16.
// (EXACT R4 version — the R6 dual-dir fuse regressed via occupancy loss.)
// Output layout (recurrence/chunk-native), indexed by recurrence STEP sidx
// (sidx = t for fwd, 1023-t for bwd):
//   xgv[blk32][b32][jl16][sc128][si8][g4]
//   idx = ((((blk*32+b)*16+jl)*128 + sc)*8 + si)*4 + g
// Block covers ALL 4 GATES x 32 hidden cols; epilogue assembles contiguous
// (4 si x 4 g) = 32 B runs in LDS, emits 2x16B vector stores.
// ---------------------------------------------------------------------------
__global__ __launch_bounds__(256) void gemm_xg(const float* __restrict__ x,
                                               const _Float16* __restrict__ WxT_f,
                                               const float* __restrict__ b_f,
                                               const _Float16* __restrict__ WxT_b,
                                               const float* __restrict__ b_b,
                                               _Float16* __restrict__ xg_f,
                                               _Float16* __restrict__ xg_b) {
    const int dir = blockIdx.z;
    const _Float16* __restrict__ WxT = dir ? WxT_b : WxT_f;
    const float* __restrict__ bias = dir ? b_b : b_f;
    _Float16* __restrict__ out = dir ? xg_b : xg_f;

    const int c0 = blockIdx.x * 32;   // hidden-col base (0..511)
    const int m0 = blockIdx.y * 128;  // row base; t0 = blockIdx.y*4

    __shared__ __align__(16) unsigned char smem[40960];
    _Float16* A_lds = (_Float16*)smem;            // [128][72]
    _Float16* B_lds = (_Float16*)(smem + 18432);  // [128][72]
    _Float16* stage = (_Float16*)smem;            // [c32][520]: b*16 + lsi*4 + g

    const int tid = threadIdx.x;
    const int wave = tid >> 6;
    const int lane = tid & 63;
    const int jn = lane & 15;
    const int quad = lane >> 4;

    f32x4 acc[2][8] = {};

    for (int k0 = 0; k0 < DD; k0 += 64) {
        // ---- stage A: 128m x 64k fp32 -> f16 LDS ----
        {
            const int kq = tid & 15;
            const int mq = tid >> 4;
#pragma unroll
            for (int i = 0; i < 8; i++) {
                const int m = mq + 16 * i;
                const int gm = m0 + m;
                const int t = gm >> 5;
                const int b = gm & 31;
                const float4 v = *(const float4*)(x + ((size_t)b * TT + t) * DD + k0 + kq * 4);
                f16x4 f;
                f.x = (_Float16)v.x; f.y = (_Float16)v.y;
                f.z = (_Float16)v.z; f.w = (_Float16)v.w;
                *(f16x4*)(A_lds + m * 72 + kq * 4) = f;
            }
        }
        // ---- stage B: 128 rows = {g*512 + c0 + c : g 0..3, c 0..31} ----
        {
            const int kq = tid & 7;
            const int nq = tid >> 3;
#pragma unroll
            for (int i = 0; i < 4; i++) {
                const int nl = nq + 32 * i;   // 0..127: g = nl>>5, c = nl&31
                const int g = nl >> 5;
                const int c = nl & 31;
                f16x8 w = *(const f16x8*)(WxT + (size_t)(g * 512 + c0 + c) * DD + k0 + kq * 8);
                *(f16x8*)(B_lds + nl * 72 + kq * 8) = w;
            }
        }
        __syncthreads();
#pragma unroll
        for (int kc = 0; kc < 64; kc += 32) {
            const f16x8 a0 = *(const f16x8*)(A_lds + (wave * 32 + jn) * 72 + kc + quad * 8);
            const f16x8 a1 = *(const f16x8*)(A_lds + (wave * 32 + 16 + jn) * 72 + kc + quad * 8);
#pragma unroll
            for (int nt = 0; nt < 8; nt++) {
                const f16x8 bb = *(const f16x8*)(B_lds + (nt * 16 + jn) * 72 + kc + quad * 8);
                acc[0][nt] = __builtin_amdgcn_mfma_f32_16x16x32_f16(a0, bb, acc[0][nt], 0, 0, 0);
                acc[1][nt] = __builtin_amdgcn_mfma_f32_16x16x32_f16(a1, bb, acc[1][nt], 0, 0, 0);
            }
        }
        __syncthreads();
    }

    // ---- epilogue: bias, assemble (si,g) runs in LDS, 16B vector stores ----
    float bv[8];
#pragma unroll
    for (int nt = 0; nt < 8; nt++)
        bv[nt] = bias[(nt >> 1) * 512 + c0 + (nt & 1) * 16 + jn];

    const int lsi = dir ? (3 - wave) : wave;
#pragma unroll
    for (int mt = 0; mt < 2; mt++) {
#pragma unroll
        for (int r = 0; r < 4; r++) {
            const int b = mt * 16 + quad * 4 + r;
#pragma unroll
            for (int nt = 0; nt < 8; nt++) {
                const int c = (nt & 1) * 16 + jn;
                stage[c * 520 + b * 16 + lsi * 4 + (nt >> 1)] =
                    (_Float16)(acc[mt][nt][r] + bv[nt]);
            }
        }
    }
    __syncthreads();

    const int sidx0 = dir ? (1020 - blockIdx.y * 4) : (blockIdx.y * 4);
    const int sc = sidx0 >> 3;
    const int si0 = sidx0 & 7;  // 0 or 4
#pragma unroll
    for (int it = 0; it < 4; it++) {
        const int p = it * 256 + tid;
        const int c = p & 31;
        const int b = p >> 5;
        const int cglob = c0 + c;
        const int blk = cglob >> 4;
        const int jl = cglob & 15;
        const f16x8* srcp = (const f16x8*)(stage + c * 520 + b * 16);
        const size_t obase =
            ((((size_t)(blk * 32 + b) * 16 + jl) * 128 + sc) * 8 + si0) * 4;
        *(f16x8*)(out + obase) = srcp[0];
        *(f16x8*)(out + obase + 8) = srcp[1];
    }
}

// ---------------------------------------------------------------------------
// Phase 2: persistent bidirectional LSTM recurrence via MFMA.
// R7: 64 blocks x 512 threads = 8 INDEPENDENT chains of 8 blocks:
//   chain = (dir, grp): dir = bid>>5, grp = (bid>>3)&3, blk = bid&7.
//   grp owns batch rows [grp*8, grp*8+8); block owns hidden cols
//   [blk*64, blk*64+64) x 4 gates. Fan-in per consumer 8 (was 16); poll
//   slice 2 u64/thread (was 4); chain h-state 8 KB (was 16).
// Waves: g = wave>>1 (gate), chalf = wave&1 (col-32 half). Per wave:
//   2 N-tiles x 16 K-chunks = 32 MFMA/step, M=8 real rows padded to 16
//   (LDS rows 8..15 pre-zeroed once -> top half of D is exactly 0, inert).
//   bfrag = 2x16 f16x8 = 128 VGPR; __launch_bounds__(512,2) caps at 256.
// Gate threads: wave = row (gb = tid>>6), lane = col (gc = tid&63) —
//   4 preacts/thread (unchanged); FC reduce = 6 shfl_xor over the wave.
//
// h exchange: sentinel-poisoned ring of 4 slots per chain, 4xf16 per u64.
//   Protocol IDENTICAL to the R4 version (3 passing rounds): validity =
//   low f16 != 0xFC00; slot for step s = s&3; producer re-poisons its own
//   (s-2) positions before the post-poll __syncthreads (vmcnt-0 drain
//   orders poison strictly before this step's h(s+1) store; IF$ is the
//   single agent-scope coherence point).
// ---------------------------------------------------------------------------
__global__ __launch_bounds__(512, 2) void lstm_persist(
    const _Float16* __restrict__ xg_f,
    const _Float16* __restrict__ xg_b,
    const _Float16* __restrict__ WhT_f,
    const _Float16* __restrict__ WhT_b,
    const float* __restrict__ wfc,
    unsigned long long* __restrict__ hring,   // [chain8][slot4][1024] u64
    _Float16* __restrict__ part) {

    __shared__ __align__(16) _Float16 h_lds[16 * 520];  // [row16][k512 pad 520]
    __shared__ float red[4 * 8 * 66];                   // [g][row8][col64 pad 66]

    const int tid = threadIdx.x;
    const int bid = blockIdx.x;
    const int dir = bid >> 5;
    const int grp = (bid >> 3) & 3;
    const int blk = bid & 7;

    const _Float16* __restrict__ xg = dir ? xg_b : xg_f;
    const _Float16* __restrict__ WhT = dir ? WhT_b : WhT_f;
    unsigned long long* hp = hring + ((size_t)(dir * 4 + grp)) * 4096;  // [slot4][1024]

    // wave roles
    const int lane = tid & 63;
    const int wave = tid >> 6;
    const int g = wave >> 1;       // gate 0..3
    const int chalf = wave & 1;    // col-32 half within block's 64 cols
    const int jl16 = lane & 15;
    const int quad = lane >> 4;

    // ---- preload Wh B-fragments into registers (once): 2 N-tiles ----
    f16x8 bfrag[2][16];
#pragma unroll
    for (int nt = 0; nt < 2; nt++) {
        const _Float16* wcol =
            WhT + (size_t)(g * 512 + blk * 64 + chalf * 32 + nt * 16 + jl16) * HH;
#pragma unroll
        for (int i = 0; i < 16; i++)
            bfrag[nt][i] = *(const f16x8*)(wcol + i * 32 + quad * 8);
    }

    // gate-thread role: wave = row, lane = col
    const int gb = tid >> 6;       // row within group, 0..7 (= wave)
    const int gc = tid & 63;       // hidden col within block's 64 (= lane)
    float c_reg = 0.0f;
    const float wfc_reg = wfc[dir * 512 + blk * 64 + gc];

    unsigned long long* hl64 = (unsigned long long*)h_lds;
    const int blk32 = blk * 4 + (gc >> 4);
    const int b_glob = grp * 8 + gb;
    const _Float16* xbase =
        xg + (((size_t)(blk32 * 32 + b_glob) * 16 + (gc & 15)) * 128) * 32;

    // producer slot (threads with gc%4==0): u64 covers cols blk*64+gc..+3
    const int prod_idx = gb * 128 + blk * 16 + (gc >> 2);
    const bool is_prod = ((gc & 3) == 0);

    // ---- zero pad rows 8..15 of h_lds once (MFMA M-pad reads zeros) ----
    for (int i = tid; i < 8 * 130; i += 512) hl64[8 * 130 + i] = 0ull;
    // (first step's post-poll __syncthreads orders this before any MFMA)

    // ---- xg chunk double-buffer: 64 B regs cover 8 steps; prefetch next ----
    f16x8 xcur[4];
    {
        const f16x8* src0 = (const f16x8*)(xbase);
#pragma unroll
        for (int q = 0; q < 4; q++) xcur[q] = src0[q];
    }

    for (int sc = 0; sc < 128; sc++) {
        f16x8 xnxt[4];
        if (sc < 127) {
            const f16x8* srcn = (const f16x8*)(xbase + (sc + 1) * 32);
#pragma unroll
            for (int q = 0; q < 4; q++) xnxt[q] = srcn[q];
        }

#pragma unroll
        for (int si = 0; si < 8; si++) {
            const int s = sc * 8 + si;
            const int t = dir ? (1023 - s) : s;

            // ---- re-poison own step-(s-2) positions (off critical path) ----
            if (s >= 2 && is_prod)
                __hip_atomic_store(hp + (size_t)((s - 2) & 3) * 1024 + prod_idx,
                                   POISON_U64, __ATOMIC_RELAXED,
                                   __HIP_MEMORY_SCOPE_AGENT);

            // ---- stage h(s): poll sentinel u64s, write arrivals to LDS ----
            // thread's slice: idx = q*512 + tid, q=0..1; row=idx>>7, c4=idx&127
            {
                const unsigned long long* __restrict__ src =
                    hp + (size_t)(s & 3) * 1024;
                unsigned int pend = 0x3u;
                int guard = 0;
                do {
                    unsigned long long v[2];
                    if (pend & 1u)
                        v[0] = __hip_atomic_load(src + tid, __ATOMIC_RELAXED,
                                                 __HIP_MEMORY_SCOPE_AGENT);
                    if (pend & 2u)
                        v[1] = __hip_atomic_load(src + 512 + tid, __ATOMIC_RELAXED,
                                                 __HIP_MEMORY_SCOPE_AGENT);
                    unsigned int got = 0;
                    if ((pend & 1u) && ((unsigned int)v[0] & 0xFFFFu) != 0xFC00u) {
                        hl64[(tid >> 7) * 130 + (tid & 127)] = v[0];
                        got |= 1u;
                    }
                    if ((pend & 2u) && ((unsigned int)v[1] & 0xFFFFu) != 0xFC00u) {
                        hl64[(4 + (tid >> 7)) * 130 + (tid & 127)] = v[1];
                        got |= 2u;
                    }
                    pend &= ~got;
                    if (pend) {
                        if (got == 0) __builtin_amdgcn_s_sleep(1);
                        if (++guard > (1 << 18)) break;  // fail visibly, never hang
                    }
                } while (pend);
            }
            __syncthreads();

            // ---- MFMA: preact [8row x 32col]/wave as 2 N-tiles x 4 chains ----
            {
                f32x4 acc[2][4] = {};
                const _Float16* hrow = h_lds + jl16 * 520 + quad * 8;
#pragma unroll
                for (int i = 0; i < 4; i++) {
                    const f16x8 h0 = *(const f16x8*)(hrow + 32 * i);
                    const f16x8 h1 = *(const f16x8*)(hrow + 32 * (i + 4));
                    const f16x8 h2 = *(const f16x8*)(hrow + 32 * (i + 8));
                    const f16x8 h3 = *(const f16x8*)(hrow + 32 * (i + 12));
#pragma unroll
                    for (int nt = 0; nt < 2; nt++) {
                        acc[nt][0] = __builtin_amdgcn_mfma_f32_16x16x32_f16(h0, bfrag[nt][i],      acc[nt][0], 0, 0, 0);
                        acc[nt][1] = __builtin_amdgcn_mfma_f32_16x16x32_f16(h1, bfrag[nt][i + 4],  acc[nt][1], 0, 0, 0);
                        acc[nt][2] = __builtin_amdgcn_mfma_f32_16x16x32_f16(h2, bfrag[nt][i + 8],  acc[nt][2], 0, 0, 0);
                        acc[nt][3] = __builtin_amdgcn_mfma_f32_16x16x32_f16(h3, bfrag[nt][i + 12], acc[nt][3], 0, 0, 0);
                    }
                }
                if (quad < 2) {  // output rows 0..7 only (rows 8..15 are zero-pad)
#pragma unroll
                    for (int nt = 0; nt < 2; nt++) {
                        const f32x4 a = (acc[nt][0] + acc[nt][1]) + (acc[nt][2] + acc[nt][3]);
#pragma unroll
                        for (int r = 0; r < 4; r++)
                            red[(g * 8 + quad * 4 + r) * 66 + chalf * 32 + nt * 16 + jl16] = a[r];
                    }
                }
            }
            __syncthreads();

            // ---- gate math + h/c update + sentinel h store + FC partial ----
            {
                const float p0 = red[(0 * 8 + gb) * 66 + gc] + (float)xcur[si >> 1][(si & 1) * 4 + 0];
                const float p1 = red[(1 * 8 + gb) * 66 + gc] + (float)xcur[si >> 1][(si & 1) * 4 + 1];
                const float p2 = red[(2 * 8 + gb) * 66 + gc] + (float)xcur[si >> 1][(si & 1) * 4 + 2];
                const float p3 = red[(3 * 8 + gb) * 66 + gc] + (float)xcur[si >> 1][(si & 1) * 4 + 3];

                const float gi = sigm(p0);
                const float gf = sigm(p1);
                const float gc_ = tanh_fast(p2);
                const float go = sigm(p3);
                c_reg = gf * c_reg + gi * gc_;
                const float hval = go * tanh_fast(c_reg);

                // pack 4 consecutive cols into one u64 (two shfls; lane == gc)
                const float hnb = __shfl_xor(hval, 1);
                union { struct { _Float16 lo, hi; } h; unsigned int u; } cvt;
                cvt.h.lo = (_Float16)hval;   // even lanes: (gc, gc+1) in order
                cvt.h.hi = (_Float16)hnb;
                const unsigned int pair2 = __shfl_xor(cvt.u, 2);  // cols gc+2,+3
                if (is_prod) {
                    const unsigned long long pv =
                        ((unsigned long long)pair2 << 32) | (unsigned long long)cvt.u;
                    __hip_atomic_store(hp + (size_t)((s + 1) & 3) * 1024 + prod_idx, pv,
                                       __ATOMIC_RELAXED, __HIP_MEMORY_SCOPE_AGENT);
                }
                // FC partial: reduce over this block's 64 cols (= full wave)
                float contrib = hval * wfc_reg;
                contrib += __shfl_xor(contrib, 1);
                contrib += __shfl_xor(contrib, 2);
                contrib += __shfl_xor(contrib, 4);
                contrib += __shfl_xor(contrib, 8);
                contrib += __shfl_xor(contrib, 16);
                contrib += __shfl_xor(contrib, 32);
                if (gc == 0)
                    part[(size_t)(t * 32 + b_glob) * 16 + dir * 8 + blk] = (_Float16)contrib;
            }
            // no trailing barrier: next step's LDS stage writes are ordered
            // after this step's MFMA reads by the post-red barrier above.
        }

        if (sc < 127) {
#pragma unroll
            for (int q = 0; q < 4; q++) xcur[q] = xnxt[q];
        }
    }
}

// ---------------------------------------------------------------------------
// Final: out[b][t] = sigmoid(b_fc + sum over 16 partials part[t][b][*])
// ---------------------------------------------------------------------------
__global__ __launch_bounds__(256) void fc_final(const _Float16* __restrict__ part,
                                                const float* __restrict__ b_fc,
                                                float* __restrict__ out) {
    const int i = blockIdx.x * 256 + threadIdx.x;  // i = b*1024 + t
    const int b = i >> 10;
    const int t = i & 1023;
    const f16x8* p = (const f16x8*)(part + (size_t)(t * 32 + b) * 16);
    float acc = b_fc[0];
#pragma unroll
    for (int q = 0; q < 2; q++) {
        const f16x8 v = p[q];
#pragma unroll
        for (int e = 0; e < 8; e++) acc += (float)v[e];
    }
    out[i] = sigm(acc);
}

extern "C" void kernel_launch(void* const* d_in, const int* in_sizes, int n_in,
                              void* d_out, int out_size, void* d_ws, size_t ws_size,
                              hipStream_t stream) {
    const float* x    = (const float*)d_in[0];
    const float* Wx_f = (const float*)d_in[1];
    const float* Wh_f = (const float*)d_in[2];
    const float* b_f  = (const float*)d_in[3];
    const float* Wx_b = (const float*)d_in[4];
    const float* Wh_b = (const float*)d_in[5];
    const float* b_b  = (const float*)d_in[6];
    const float* W_fc = (const float*)d_in[7];
    const float* b_fc = (const float*)d_in[8];
    float* out = (float*)d_out;

    // Workspace layout (bytes):
    //   xgv_f f16 chunk-native          : 134,217,728
    //   xgv_b f16 chunk-native          : 134,217,728
    //   WxT_f f16 [2048][1024]          : 4,194,304   <- `part` (1 MB) aliases
    //                                                    this after gemm_xg
    //   WxT_b f16 [2048][1024]          : 4,194,304   <- hring (256 KB)
    //                                                    aliases this after gemm_xg
    //   WhT_f f16 [2048][512]           : 2,097,152
    //   WhT_b f16 [2048][512]           : 2,097,152
    // total 281,018,368 (same as previous passing rounds).
    // Order: transposes -> gemm_xg -> init (poisons hring in dead WxT_b) ->
    //        lstm_persist -> fc_final.
    const size_t XG       = 134217728ULL;
    const size_t WXT_OFF  = 2 * XG;                        // 268,435,456
    const size_t WHT_OFF  = WXT_OFF + 2 * 4194304ULL;      // 276,824,064
    const size_t need     = WHT_OFF + 2 * 2097152ULL;      // 281,018,368
    if (ws_size < need) return;  // fail loudly via mismatch

    uint8_t* ws = (uint8_t*)d_ws;
    _Float16* xg_f = (_Float16*)ws;
    _Float16* xg_b = (_Float16*)(ws + XG);
    _Float16* WxT_f = (_Float16*)(ws + WXT_OFF);
    _Float16* WxT_b = (_Float16*)(ws + WXT_OFF + 4194304ULL);
    _Float16* WhT_f = (_Float16*)(ws + WHT_OFF);
    _Float16* WhT_b = (_Float16*)(ws + WHT_OFF + 2097152ULL);
    _Float16* part  = (_Float16*)(ws + WXT_OFF);                 // alias WxT_f
    unsigned long long* hring =
        (unsigned long long*)(ws + WXT_OFF + 4194304ULL);        // alias WxT_b

    // pre-transpose weights to f16 [n][k]
    transpose_f16<<<dim3(64, 32), 256, 0, stream>>>(Wx_f, WxT_f, 1024, 2048);
    transpose_f16<<<dim3(64, 32), 256, 0, stream>>>(Wx_b, WxT_b, 1024, 2048);
    transpose_f16<<<dim3(64, 16), 256, 0, stream>>>(Wh_f, WhT_f, 512, 2048);
    transpose_f16<<<dim3(64, 16), 256, 0, stream>>>(Wh_b, WhT_b, 512, 2048);

    // phase 1: input projections (MFMA f16), R4 split-dir grid
    gemm_xg<<<dim3(16, 256, 2), 256, 0, stream>>>(
        x, WxT_f, b_f, WxT_b, b_b, xg_f, xg_b);

    // init sentinel rings (8 chains; slot0 = zeros = valid h(0)) — after
    // gemm_xg since it aliases WxT_b
    init_kernel<<<128, 256, 0, stream>>>(hring);

    // phase 2: persistent recurrence (64 blocks = 8 chains x 8, co-resident)
    lstm_persist<<<64, 512, 0, stream>>>(
        xg_f, xg_b, WhT_f, WhT_b, W_fc, hring, part);

    // epilogue: reduce FC partials + bias + sigmoid
    fc_final<<<(BB * TT) / 256, 256, 0, stream>>>(part, b_fc, out);
}